// Round 5
// baseline (430.141 us; speedup 1.0000x reference)
//
#include <hip/hip_runtime.h>
#include <math.h>

#define BB  256
#define TCC 256
#define DD  2048
#define PSTRIDE 2056   // attn partial stride in floats: [m,l,pad..8, acc 2048]

typedef float4 f4;
typedef float __attribute__((ext_vector_type(4))) fv4;   // ok for nontemporal builtins

// ---------------------------------------------------------------------------
// Kernel A: hw = h_dec @ W  (f32), split-K into 4 partials stored in d_ws.
// grid (32 e-tiles, 4 b-tiles, 4 k-splits), 256 threads.  (unchanged)
// ---------------------------------------------------------------------------
__global__ __launch_bounds__(256) void hw_gemm_partial(
    const float* __restrict__ h,     // [B][D]
    const float* __restrict__ W,     // [D][D]
    float* __restrict__ part)        // [4][B][D]
{
    __shared__ float hs[32][68];     // [d][b] transposed
    __shared__ float wsm[32][64];    // [d][e]

    const int tid = threadIdx.x;
    const int e0 = blockIdx.x * 64;
    const int b0 = blockIdx.y * 64;
    const int z  = blockIdx.z;

    float acc[4][4];
    #pragma unroll
    for (int i = 0; i < 4; i++)
        #pragma unroll
        for (int j = 0; j < 4; j++) acc[i][j] = 0.f;

    const int ie = tid & 15;
    const int ib = tid >> 4;

    const int hr = tid >> 2;
    const int hc = (tid & 3) * 8;
    const int wr = tid >> 3;
    const int wc = (tid & 7) * 8;

    for (int d0 = z * 512; d0 < z * 512 + 512; d0 += 32) {
        f4 ha = *(const f4*)&h[(size_t)(b0 + hr) * DD + d0 + hc];
        f4 hb = *(const f4*)&h[(size_t)(b0 + hr) * DD + d0 + hc + 4];
        hs[hc + 0][hr] = ha.x; hs[hc + 1][hr] = ha.y;
        hs[hc + 2][hr] = ha.z; hs[hc + 3][hr] = ha.w;
        hs[hc + 4][hr] = hb.x; hs[hc + 5][hr] = hb.y;
        hs[hc + 6][hr] = hb.z; hs[hc + 7][hr] = hb.w;
        f4 wa = *(const f4*)&W[(size_t)(d0 + wr) * DD + e0 + wc];
        f4 wb = *(const f4*)&W[(size_t)(d0 + wr) * DD + e0 + wc + 4];
        *(f4*)&wsm[wr][wc]     = wa;
        *(f4*)&wsm[wr][wc + 4] = wb;
        __syncthreads();

        #pragma unroll
        for (int dd = 0; dd < 32; dd++) {
            f4 hv = *(const f4*)&hs[dd][ib * 4];
            f4 wv = *(const f4*)&wsm[dd][ie * 4];
            float hvv[4] = {hv.x, hv.y, hv.z, hv.w};
            float wvv[4] = {wv.x, wv.y, wv.z, wv.w};
            #pragma unroll
            for (int i = 0; i < 4; i++)
                #pragma unroll
                for (int j = 0; j < 4; j++)
                    acc[i][j] += hvv[i] * wvv[j];
        }
        __syncthreads();
    }

    #pragma unroll
    for (int i = 0; i < 4; i++) {
        f4 v = make_float4(acc[i][0], acc[i][1], acc[i][2], acc[i][3]);
        *(f4*)&part[((size_t)z * BB + b0 + ib * 4 + i) * DD + e0 + ie * 4] = v;
    }
}

// ---------------------------------------------------------------------------
// Kernel B v4: wave-autonomous fused attention + concat copy, 256-thread
// blocks (no VGPR spill), 2-deep register double-buffer prefetch.
// grid (4 chunks, B): block handles timesteps [64c, 64c+64) of batch b with
// 4 waves x 16 timesteps. Per-wave online softmax, zero barriers in loop;
// 4 wave-states merged in-block via LDS; block partial (m,l,acc[2048])
// written to d_ws for kernel C.
// ---------------------------------------------------------------------------
__global__ __launch_bounds__(256, 3) void attn_part(
    const float* __restrict__ prev,    // [B][TC][D]
    const unsigned char* __restrict__ maskb,
    const float* __restrict__ part,    // [4][B][D] hw gemm partials
    float* __restrict__ apart,         // [B][4][PSTRIDE] attn partials
    float* __restrict__ out)           // [B*D ctx | B*(TC+1)*D new_prev]
{
    __shared__ float hw[DD];
    __shared__ float ctxs[DD];
    __shared__ float gm[4], gl[4];

    const int c   = blockIdx.x;
    const int b   = blockIdx.y;
    const int tid = threadIdx.x;

    // reduce the 4 split-K gemm partials -> hw row in LDS (8 floats/thread)
    {
        const int k = tid * 8;
        const float* p0 = part + (size_t)b * DD + k;
        fv4 a0 = *(const fv4*)(p0);
        fv4 a1 = *(const fv4*)(p0 + 4);
        #pragma unroll
        for (int z = 1; z < 4; ++z) {
            const float* pz = part + ((size_t)z * BB + b) * DD + k;
            a0 += *(const fv4*)(pz);
            a1 += *(const fv4*)(pz + 4);
        }
        *(fv4*)&hw[k]     = a0;
        *(fv4*)&hw[k + 4] = a1;
    }

    // mask dtype-layout detection: bool bytes -> nonzero bytes at k%4!=0
    int nz = 0;
    #pragma unroll
    for (int k = 1; k < 64; k++)
        if ((k & 3) != 0) nz += (maskb[k] != 0);
    const bool boolLayout = (nz > 0);
    const int* maski = (const int*)maskb;

    __syncthreads();

    const int w  = tid >> 6;     // wave 0..3
    const int ld = tid & 63;     // lane
    const int t0 = c * 64 + w * 16;

    const float* pb = prev + (size_t)b * TCC * DD + 4 * ld;
    float* cp = out + (size_t)BB * DD + (size_t)b * (TCC + 1) * DD + 4 * ld;

    fv4 acc[8];
    #pragma unroll
    for (int j = 0; j < 8; j++) acc[j] = (fv4)(0.f);
    float m = -INFINITY, l = 0.f;

    fv4 va[8], vb[8];

    auto prefetch = [&](fv4* v, int t) {
        const float* s = pb + (size_t)t * DD;
        #pragma unroll
        for (int j = 0; j < 8; ++j)
            v[j] = __builtin_nontemporal_load((const fv4*)(s + 256 * j));
    };

    auto process = [&](fv4* v, int t) {
        float* d = cp + (size_t)t * DD;
        #pragma unroll
        for (int j = 0; j < 8; ++j)
            __builtin_nontemporal_store(v[j], (fv4*)(d + 256 * j));

        float p = 0.f;
        #pragma unroll
        for (int j = 0; j < 8; ++j) {
            const fv4 hv = *(const fv4*)&hw[4 * ld + 256 * j];
            p += v[j].x * hv.x + v[j].y * hv.y + v[j].z * hv.z + v[j].w * hv.w;
        }
        #pragma unroll
        for (int off = 32; off; off >>= 1) p += __shfl_xor(p, off, 64);

        const bool mk = boolLayout ? (maskb[(size_t)b * TCC + t] != 0)
                                   : (maski[(size_t)b * TCC + t] != 0);
        if (mk) {
            if (p > m) {
                const float s = __expf(m - p);   // m=-inf first time -> 0
                l *= s;
                #pragma unroll
                for (int j = 0; j < 8; j++) acc[j] *= s;
                m = p;
            }
            const float wgt = __expf(p - m);
            l += wgt;
            #pragma unroll
            for (int j = 0; j < 8; j++) acc[j] += wgt * v[j];
        }
    };

    // software-pipelined: 2 buffers, prefetch issued right after buffer reuse
    prefetch(va, t0);
    prefetch(vb, t0 + 1);
    #pragma unroll 1
    for (int k = 0; k < 14; k += 2) {
        process(va, t0 + k);
        prefetch(va, t0 + k + 2);
        process(vb, t0 + k + 1);
        prefetch(vb, t0 + k + 3);
    }
    process(va, t0 + 14);
    process(vb, t0 + 15);

    // merge the 4 wave-states (flash-style) into a block partial
    if (ld == 0) { gm[w] = m; gl[w] = l; }
    __syncthreads();
    const float mb = fmaxf(fmaxf(gm[0], gm[1]), fmaxf(gm[2], gm[3]));
    float Lb = 0.f;
    #pragma unroll
    for (int q = 0; q < 4; q++) Lb += gl[q] * __expf(gm[q] - mb);
    const float f = __expf(m - mb);

    for (int ph = 0; ph < 4; ++ph) {
        if (w == ph) {
            #pragma unroll
            for (int j = 0; j < 8; ++j) {
                fv4* cx = (fv4*)&ctxs[4 * ld + 256 * j];
                if (ph == 0) *cx = f * acc[j];
                else         *cx += f * acc[j];
            }
        }
        __syncthreads();
    }

    float* bp = apart + ((size_t)b * 4 + c) * PSTRIDE;
    if (tid == 0) { bp[0] = mb; bp[1] = Lb; }
    {
        const int k = tid * 8;
        *(fv4*)(bp + 8 + k)     = *(const fv4*)&ctxs[k];
        *(fv4*)(bp + 8 + k + 4) = *(const fv4*)&ctxs[k + 4];
    }
}

// ---------------------------------------------------------------------------
// Kernel C: merge the 4 chunk partials per batch row -> ctx; append h_dec.
// grid (B), 256 threads, ~10 MB traffic.
// ---------------------------------------------------------------------------
__global__ __launch_bounds__(256) void attn_merge(
    const float* __restrict__ h_dec,
    const float* __restrict__ apart,   // [B][4][PSTRIDE]
    float* __restrict__ out)
{
    const int b   = blockIdx.x;
    const int tid = threadIdx.x;
    const float* base = apart + (size_t)b * 4 * PSTRIDE;

    float mq[4], lq[4];
    #pragma unroll
    for (int q = 0; q < 4; ++q) {
        mq[q] = base[q * PSTRIDE];
        lq[q] = base[q * PSTRIDE + 1];
    }
    const float ms = fmaxf(fmaxf(mq[0], mq[1]), fmaxf(mq[2], mq[3]));
    float L = 0.f;
    float fq[4];
    #pragma unroll
    for (int q = 0; q < 4; ++q) { fq[q] = __expf(mq[q] - ms); L += lq[q] * fq[q]; }
    const float invL = 1.0f / L;

    const int k = tid * 8;
    fv4 c0 = (fv4)(0.f), c1 = (fv4)(0.f);
    #pragma unroll
    for (int q = 0; q < 4; ++q) {
        const float* a = base + q * PSTRIDE + 8 + k;
        c0 += fq[q] * *(const fv4*)(a);
        c1 += fq[q] * *(const fv4*)(a + 4);
    }
    *(fv4*)&out[(size_t)b * DD + k]     = c0 * invL;
    *(fv4*)&out[(size_t)b * DD + k + 4] = c1 * invL;

    // append h_dec as row TC of new_prev
    const float* hp = h_dec + (size_t)b * DD + k;
    float* op = out + (size_t)BB * DD + ((size_t)b * (TCC + 1) + TCC) * DD + k;
    *(fv4*)op       = *(const fv4*)hp;
    *(fv4*)(op + 4) = *(const fv4*)(hp + 4);
}

extern "C" void kernel_launch(void* const* d_in, const int* in_sizes, int n_in,
                              void* d_out, int out_size, void* d_ws, size_t ws_size,
                              hipStream_t stream) {
    const float* h_dec = (const float*)d_in[0];
    const float* prev  = (const float*)d_in[1];
    const unsigned char* maskb = (const unsigned char*)d_in[2];
    const float* W = (const float*)d_in[3];
    float* out   = (float*)d_out;
    float* part  = (float*)d_ws;                       // 8 MB gemm partials
    float* apart = part + (size_t)4 * BB * DD;         // 8.4 MB attn partials

    hipLaunchKernelGGL(hw_gemm_partial, dim3(32, 4, 4), dim3(256), 0, stream,
                       h_dec, W, part);
    hipLaunchKernelGGL(attn_part, dim3(4, BB), dim3(256), 0, stream,
                       prev, maskb, part, apart, out);
    hipLaunchKernelGGL(attn_merge, dim3(BB), dim3(256), 0, stream,
                       h_dec, apart, out);
}

// Round 6
// 275.022 us; speedup vs baseline: 1.5640x; 1.5640x over previous
//
#include <hip/hip_runtime.h>
#include <math.h>

#define BB  256
#define TCC 256
#define DD  2048

typedef float4 f4;
typedef float __attribute__((ext_vector_type(4))) fv4;   // ok for nontemporal builtins

// ---------------------------------------------------------------------------
// Kernel A: hw = h_dec @ W  (f32), split-K into 4 partials stored in d_ws.
// grid (32 e-tiles, 4 b-tiles, 4 k-splits), 256 threads.  (unchanged)
// ---------------------------------------------------------------------------
__global__ __launch_bounds__(256) void hw_gemm_partial(
    const float* __restrict__ h,     // [B][D]
    const float* __restrict__ W,     // [D][D]
    float* __restrict__ part)        // [4][B][D]
{
    __shared__ float hs[32][68];     // [d][b] transposed
    __shared__ float wsm[32][64];    // [d][e]

    const int tid = threadIdx.x;
    const int e0 = blockIdx.x * 64;
    const int b0 = blockIdx.y * 64;
    const int z  = blockIdx.z;

    float acc[4][4];
    #pragma unroll
    for (int i = 0; i < 4; i++)
        #pragma unroll
        for (int j = 0; j < 4; j++) acc[i][j] = 0.f;

    const int ie = tid & 15;
    const int ib = tid >> 4;

    const int hr = tid >> 2;
    const int hc = (tid & 3) * 8;
    const int wr = tid >> 3;
    const int wc = (tid & 7) * 8;

    for (int d0 = z * 512; d0 < z * 512 + 512; d0 += 32) {
        f4 ha = *(const f4*)&h[(size_t)(b0 + hr) * DD + d0 + hc];
        f4 hb = *(const f4*)&h[(size_t)(b0 + hr) * DD + d0 + hc + 4];
        hs[hc + 0][hr] = ha.x; hs[hc + 1][hr] = ha.y;
        hs[hc + 2][hr] = ha.z; hs[hc + 3][hr] = ha.w;
        hs[hc + 4][hr] = hb.x; hs[hc + 5][hr] = hb.y;
        hs[hc + 6][hr] = hb.z; hs[hc + 7][hr] = hb.w;
        f4 wa = *(const f4*)&W[(size_t)(d0 + wr) * DD + e0 + wc];
        f4 wb = *(const f4*)&W[(size_t)(d0 + wr) * DD + e0 + wc + 4];
        *(f4*)&wsm[wr][wc]     = wa;
        *(f4*)&wsm[wr][wc + 4] = wb;
        __syncthreads();

        #pragma unroll
        for (int dd = 0; dd < 32; dd++) {
            f4 hv = *(const f4*)&hs[dd][ib * 4];
            f4 wv = *(const f4*)&wsm[dd][ie * 4];
            float hvv[4] = {hv.x, hv.y, hv.z, hv.w};
            float wvv[4] = {wv.x, wv.y, wv.z, wv.w};
            #pragma unroll
            for (int i = 0; i < 4; i++)
                #pragma unroll
                for (int j = 0; j < 4; j++)
                    acc[i][j] += hvv[i] * wvv[j];
        }
        __syncthreads();
    }

    #pragma unroll
    for (int i = 0; i < 4; i++) {
        f4 v = make_float4(acc[i][0], acc[i][1], acc[i][2], acc[i][3]);
        *(f4*)&part[((size_t)z * BB + b0 + ib * 4 + i) * DD + e0 + ie * 4] = v;
    }
}

// ---------------------------------------------------------------------------
// Kernel B v5: = R3's attn_fused2 (wave-autonomous, no loop barriers, 8
// loads in flight per wave) with PLAIN stores (nt stores inflated HBM
// writes 1.75x per R5 counters). nt loads kept for the use-once stream.
// One block per b, 16 waves; wave w owns timesteps [16w, 16w+16).
// ---------------------------------------------------------------------------
__global__ __launch_bounds__(1024) void attn_fused5(
    const float* __restrict__ h_dec,   // [B][D]
    const float* __restrict__ prev,    // [B][TC][D]
    const unsigned char* __restrict__ maskb,
    const float* __restrict__ part,    // [4][B][D] hw partials
    float* __restrict__ out)           // [B*D ctx | B*(TC+1)*D new_prev]
{
    __shared__ float hw[DD];
    __shared__ float ctx[DD];
    __shared__ float gm[16], gl[16];

    const int b   = blockIdx.x;
    const int tid = threadIdx.x;

    // reduce the 4 split-K partials -> hw row; zero ctx accumulator
    for (int k = tid; k < DD; k += 1024) {
        hw[k] = part[(size_t)b * DD + k]
              + part[((size_t)BB + b) * DD + k]
              + part[((size_t)2 * BB + b) * DD + k]
              + part[((size_t)3 * BB + b) * DD + k];
        ctx[k] = 0.f;
    }

    // mask dtype-layout detection: bool bytes -> nonzero bytes at k%4!=0
    int nz = 0;
    #pragma unroll
    for (int k = 1; k < 64; k++)
        if ((k & 3) != 0) nz += (maskb[k] != 0);
    const bool boolLayout = (nz > 0);
    const int* maski = (const int*)maskb;

    __syncthreads();

    const int w  = tid >> 6;     // wave 0..15
    const int ld = tid & 63;     // lane

    const float* pb = prev + (size_t)b * TCC * DD + 4 * ld;
    float* cp = out + (size_t)BB * DD + (size_t)b * (TCC + 1) * DD + 4 * ld;

    fv4 acc[8];
    #pragma unroll
    for (int j = 0; j < 8; j++) acc[j] = (fv4)(0.f);
    float m = -INFINITY, l = 0.f;

    for (int k = 0; k < 16; ++k) {
        const int t = w * 16 + k;
        const fv4* src = (const fv4*)(pb + (size_t)t * DD);
        fv4 v[8];
        #pragma unroll
        for (int j = 0; j < 8; ++j) v[j] = __builtin_nontemporal_load(src + 64 * j);

        fv4* dst = (fv4*)(cp + (size_t)t * DD);
        #pragma unroll
        for (int j = 0; j < 8; ++j) dst[64 * j] = v[j];    // PLAIN stores

        float p = 0.f;
        #pragma unroll
        for (int j = 0; j < 8; ++j) {
            const fv4 hv = *(const fv4*)&hw[4 * ld + 256 * j];
            p += v[j].x * hv.x + v[j].y * hv.y + v[j].z * hv.z + v[j].w * hv.w;
        }
        #pragma unroll
        for (int off = 32; off; off >>= 1) p += __shfl_xor(p, off, 64);

        const bool mk = boolLayout ? (maskb[(size_t)b * TCC + t] != 0)
                                   : (maski[(size_t)b * TCC + t] != 0);
        if (mk) {
            if (p > m) {
                const float s = __expf(m - p);   // m=-inf first time -> 0
                l *= s;
                #pragma unroll
                for (int j = 0; j < 8; j++) acc[j] *= s;
                m = p;
            }
            const float wgt = __expf(p - m);
            l += wgt;
            #pragma unroll
            for (int j = 0; j < 8; j++) acc[j] += wgt * v[j];
        }
    }

    if (ld == 0) { gm[w] = m; gl[w] = l; }
    __syncthreads();

    float mstar = -INFINITY;
    #pragma unroll
    for (int q = 0; q < 16; q++) mstar = fmaxf(mstar, gm[q]);
    float L = 0.f;
    #pragma unroll
    for (int q = 0; q < 16; q++) L += gl[q] * __expf(gm[q] - mstar);
    const float f = __expf(m - mstar);

    for (int ph = 0; ph < 16; ++ph) {
        if (w == ph) {
            #pragma unroll
            for (int j = 0; j < 8; ++j) {
                fv4* c = (fv4*)&ctx[4 * ld + 256 * j];
                *c += f * acc[j];
            }
        }
        __syncthreads();
    }

    const float invL = 1.0f / L;
    for (int k = tid; k < DD; k += 1024)
        out[(size_t)b * DD + k] = ctx[k] * invL;
    // append h_dec as row TC of new_prev
    for (int k = tid; k < DD; k += 1024)
        out[(size_t)BB * DD + ((size_t)b * (TCC + 1) + TCC) * DD + k] =
            h_dec[(size_t)b * DD + k];
}

extern "C" void kernel_launch(void* const* d_in, const int* in_sizes, int n_in,
                              void* d_out, int out_size, void* d_ws, size_t ws_size,
                              hipStream_t stream) {
    const float* h_dec = (const float*)d_in[0];
    const float* prev  = (const float*)d_in[1];
    const unsigned char* maskb = (const unsigned char*)d_in[2];
    const float* W = (const float*)d_in[3];
    float* out  = (float*)d_out;
    float* part = (float*)d_ws;   // 4 * B * D * 4 = 8 MB of scratch

    hipLaunchKernelGGL(hw_gemm_partial, dim3(32, 4, 4), dim3(256), 0, stream,
                       h_dec, W, part);
    hipLaunchKernelGGL(attn_fused5, dim3(BB), dim3(1024), 0, stream,
                       h_dec, prev, maskb, part, out);
}